// Round 19
// baseline (887.680 us; speedup 1.0000x reference)
//
#include <hip/hip_runtime.h>
#include <hip/hip_fp16.h>

#define N_NODES 500000
#define N_EDGES 16000000

// level-1: super-buckets of 8192 dst nodes
#define SB_BITS 13
#define SB_SIZE (1 << SB_BITS)                               // 8192
#define NSUPER ((N_NODES + SB_SIZE - 1) / SB_SIZE)           // 62
#define CAP1 270336                                          // mean 262144 + 16 sigma
// level-2: buckets of 512 dst nodes
#define BKT_BITS 9
#define BKT_SIZE (1 << BKT_BITS)                             // 512
#define NBUCKET ((N_NODES + BKT_SIZE - 1) / BKT_SIZE)        // 977
#define BKT_CAP 17408                                        // mean 16376 + 8 sigma (68KB stage)
// src-quartile sub-key (4 x 131072-node ranges)
#define QBITS 2
#define NKEY (BKT_SIZE << QBITS)                             // 2048
// bin1 geometry (977 blocks, ~4/CU)
#define B1_EPT 64
#define B1_CHUNK (256 * B1_EPT)                              // 16384 edges
#define B1_NBLK ((N_EDGES + B1_CHUNK - 1) / B1_CHUNK)        // 977
#define B1_VQ (B1_EPT / 4)                                   // 16 int4/thread
#define NV4 (N_EDGES / 4)
// bin2 geometry (992 blocks)
#define B2_PER_SUPER 16

typedef unsigned int u32x2 __attribute__((ext_vector_type(2)));
typedef unsigned int u32x4 __attribute__((ext_vector_type(4)));
typedef float f32x2 __attribute__((ext_vector_type(2)));
typedef float f32x4 __attribute__((ext_vector_type(4)));

__device__ __forceinline__ unsigned int h2u(__half2 h) { return *(unsigned int*)&h; }
__device__ __forceinline__ float2 u2f2(unsigned int u) { return __half22float2(*(__half2*)&u); }

// ---------------------------------------------------------------------------
__global__ __launch_bounds__(512) void init_bcur_kernel(
    int* __restrict__ bcur1, int* __restrict__ bcur2)
{
    int i = blockIdx.x * 512 + threadIdx.x;
    if (i < NSUPER) bcur1[i] = i * CAP1;
    if (i < NBUCKET) bcur2[i] = i * BKT_CAP;
}

// ---------------------------------------------------------------------------
// bin1: edges -> 62 super-bucket regions. pairs1[pos] = (src<<13)|(dst&8191).
// 4 replicated LDS histograms/cursors (one per wave) to cut same-address
// atomic serialization ~4x.
// ---------------------------------------------------------------------------
__global__ __launch_bounds__(256) void bin1_kernel(
    const int* __restrict__ src, const int* __restrict__ dst,
    int* __restrict__ bcur1, unsigned int* __restrict__ pairs1)
{
    __shared__ int lh[4][64];    // counts -> absolute cursors
    const int4* dst4 = (const int4*)dst;
    const int4* src4 = (const int4*)src;
    int t = threadIdx.x;
    int w = t >> 6;              // wave id 0..3
    long v0 = (long)blockIdx.x * (B1_CHUNK / 4);

    ((int*)lh)[t] = 0;
    __syncthreads();

#pragma unroll 4
    for (int q = 0; q < B1_VQ; ++q) {
        long v = v0 + q * 256 + t;
        if (v < NV4) {
            int4 d = dst4[v];
            atomicAdd(&lh[w][d.x >> SB_BITS], 1);
            atomicAdd(&lh[w][d.y >> SB_BITS], 1);
            atomicAdd(&lh[w][d.z >> SB_BITS], 1);
            atomicAdd(&lh[w][d.w >> SB_BITS], 1);
        }
    }
    __syncthreads();

    if (t < NSUPER) {
        int c0 = lh[0][t], c1 = lh[1][t], c2 = lh[2][t], c3 = lh[3][t];
        int total = c0 + c1 + c2 + c3;
        int g = total ? atomicAdd(&bcur1[t], total) : 0;
        lh[0][t] = g;
        lh[1][t] = g + c0;
        lh[2][t] = g + c0 + c1;
        lh[3][t] = g + c0 + c1 + c2;
    }
    __syncthreads();

#pragma unroll 4
    for (int q = 0; q < B1_VQ; ++q) {
        long v = v0 + q * 256 + t;
        if (v < NV4) {
            int4 d = dst4[v];
            int4 s = src4[v];
            {
                int r = atomicAdd(&lh[w][d.x >> SB_BITS], 1);
                pairs1[r] = ((unsigned int)s.x << SB_BITS) | (unsigned int)(d.x & (SB_SIZE - 1));
            }
            {
                int r = atomicAdd(&lh[w][d.y >> SB_BITS], 1);
                pairs1[r] = ((unsigned int)s.y << SB_BITS) | (unsigned int)(d.y & (SB_SIZE - 1));
            }
            {
                int r = atomicAdd(&lh[w][d.z >> SB_BITS], 1);
                pairs1[r] = ((unsigned int)s.z << SB_BITS) | (unsigned int)(d.z & (SB_SIZE - 1));
            }
            {
                int r = atomicAdd(&lh[w][d.w >> SB_BITS], 1);
                pairs1[r] = ((unsigned int)s.w << SB_BITS) | (unsigned int)(d.w & (SB_SIZE - 1));
            }
        }
    }
}

// ---------------------------------------------------------------------------
// bin2: 16 blocks per super; contiguous slice of pairs1 -> 16 sub-buckets.
// 8 replicated 16-counter histograms/cursors (one per half-wave).
// pairs2[pos] = (src<<9)|(dst&511).
// ---------------------------------------------------------------------------
__global__ __launch_bounds__(256) void bin2_kernel(
    const int* __restrict__ bcur1, int* __restrict__ bcur2,
    const unsigned int* __restrict__ pairs1, unsigned int* __restrict__ pairs2)
{
    __shared__ int lh[8][16];    // counts -> absolute cursors
    int s = blockIdx.x >> 4;
    int blk = blockIdx.x & 15;
    int t = threadIdx.x;
    int w = t >> 5;              // half-wave id 0..7
    int count = bcur1[s] - s * CAP1;
    int chunk = (((count + B2_PER_SUPER - 1) / B2_PER_SUPER) + 3) & ~3;
    int lo = blk * chunk;
    int hi = lo + chunk; if (hi > count) hi = count;
    int len = hi > lo ? hi - lo : 0;
    const unsigned int* base = pairs1 + (size_t)s * CAP1 + lo;
    const uint4* p4 = (const uint4*)base;
    int nv = len >> 2;

    if (t < 128) ((int*)lh)[t] = 0;
    __syncthreads();

    for (int i = t; i < nv; i += 256) {
        uint4 p = p4[i];
        atomicAdd(&lh[w][(p.x & (SB_SIZE - 1)) >> BKT_BITS], 1);
        atomicAdd(&lh[w][(p.y & (SB_SIZE - 1)) >> BKT_BITS], 1);
        atomicAdd(&lh[w][(p.z & (SB_SIZE - 1)) >> BKT_BITS], 1);
        atomicAdd(&lh[w][(p.w & (SB_SIZE - 1)) >> BKT_BITS], 1);
    }
    if (t < (len & 3))
        atomicAdd(&lh[w][(base[(nv << 2) + t] & (SB_SIZE - 1)) >> BKT_BITS], 1);
    __syncthreads();

    if (t < 16) {
        int c[8];
        int total = 0;
#pragma unroll
        for (int k = 0; k < 8; ++k) { c[k] = lh[k][t]; total += c[k]; }
        int g = total ? atomicAdd(&bcur2[(s << 4) | t], total) : 0;
#pragma unroll
        for (int k = 0; k < 8; ++k) { lh[k][t] = g; g += c[k]; }
    }
    __syncthreads();

    for (int i = t; i < nv; i += 256) {
        uint4 p = p4[i];
#pragma unroll
        for (int q = 0; q < 4; ++q) {
            unsigned int e = (q == 0) ? p.x : (q == 1) ? p.y : (q == 2) ? p.z : p.w;
            int sub = (int)((e & (SB_SIZE - 1)) >> BKT_BITS);
            int r = atomicAdd(&lh[w][sub], 1);
            pairs2[r] = ((e >> SB_BITS) << BKT_BITS) | (e & (BKT_SIZE - 1));
        }
    }
    if (t < (len & 3)) {
        unsigned int e = base[(nv << 2) + t];
        int sub = (int)((e & (SB_SIZE - 1)) >> BKT_BITS);
        int r = atomicAdd(&lh[w][sub], 1);
        pairs2[r] = ((e >> SB_BITS) << BKT_BITS) | (e & (BKT_SIZE - 1));
    }
}

// ---------------------------------------------------------------------------
__global__ __launch_bounds__(512) void bucket_scan_kernel(
    const int* __restrict__ bcur2, int* __restrict__ bbase)
{
    __shared__ int sdata[512];
    int t = threadIdx.x;
    int i0 = t * 2;
    int v0 = (i0 < NBUCKET) ? (bcur2[i0] - i0 * BKT_CAP) : 0;
    int v1 = (i0 + 1 < NBUCKET) ? (bcur2[i0 + 1] - (i0 + 1) * BKT_CAP) : 0;
    int s = v0 + v1;
    sdata[t] = s;
    __syncthreads();
    for (int o = 1; o < 512; o <<= 1) {
        int tmp = (t >= o) ? sdata[t - o] : 0;
        __syncthreads();
        sdata[t] += tmp;
        __syncthreads();
    }
    int run = sdata[t] - s;
    if (i0 < NBUCKET) bbase[i0] = run;
    if (i0 + 1 < NBUCKET) bbase[i0 + 1] = run + v0;
    if (i0 == NBUCKET - 1) bbase[NBUCKET] = run + v0;
    if (i0 + 1 == NBUCKET - 1) bbase[NBUCKET] = run + v0 + v1;
}

// ---------------------------------------------------------------------------
// One block (512 threads) per 512-node bucket. 2048-key histogram
// (key = (low9<<2)|src_quartile) + scan -> off4[node*4+q] + cursors; single
// placement pass into 68KB LDS stage; coalesced nt flush. Layer-1 agg fused.
// ---------------------------------------------------------------------------
__global__ __launch_bounds__(512) void bucket_sort512_kernel(
    const int* __restrict__ bcur2, const int* __restrict__ bbase,
    const unsigned int* __restrict__ pairs2, const float* __restrict__ xfeat,
    int* __restrict__ off4, int* __restrict__ sorted_src,
    float* __restrict__ agg1)
{
    __shared__ int   stage[BKT_CAP];     // 68 KB (scan scratch in [0..511] first)
    __shared__ int   lh[NKEY];           // 8 KB
    __shared__ float laccum[BKT_SIZE];   // 2 KB
    int b = blockIdx.x;
    int t = threadIdx.x;
    int base_node = b << BKT_BITS;
    size_t pstart = (size_t)b * BKT_CAP;
    int count = bcur2[b] - b * BKT_CAP;
    int cstart = bbase[b];

    lh[t] = 0; lh[512 + t] = 0; lh[1024 + t] = 0; lh[1536 + t] = 0;
    laccum[t & (BKT_SIZE - 1)] = 0.0f;
    __syncthreads();

    int nv = count >> 2;
    const uint4* p4 = (const uint4*)(pairs2 + pstart);
    for (int i = t; i < nv; i += 512) {
        uint4 p = p4[i];
        atomicAdd(&lh[((p.x & (BKT_SIZE - 1)) << QBITS) | (p.x >> 26)], 1);
        atomicAdd(&lh[((p.y & (BKT_SIZE - 1)) << QBITS) | (p.y >> 26)], 1);
        atomicAdd(&lh[((p.z & (BKT_SIZE - 1)) << QBITS) | (p.z >> 26)], 1);
        atomicAdd(&lh[((p.w & (BKT_SIZE - 1)) << QBITS) | (p.w >> 26)], 1);
    }
    if (t < (count & 3)) {
        unsigned int pe = pairs2[pstart + (nv << 2) + t];
        atomicAdd(&lh[((pe & (BKT_SIZE - 1)) << QBITS) | (pe >> 26)], 1);
    }
    __syncthreads();

    int i0 = t * 4;
    int c0 = lh[i0], c1 = lh[i0 + 1], c2 = lh[i0 + 2], c3 = lh[i0 + 3];
    int s = c0 + c1 + c2 + c3;
    stage[t] = s;
    __syncthreads();
    for (int o = 1; o < 512; o <<= 1) {
        int tmp = (t >= o) ? stage[t - o] : 0;
        __syncthreads();
        stage[t] += tmp;
        __syncthreads();
    }
    int run = cstart + stage[t] - s;
    int vals[4] = {c0, c1, c2, c3};
#pragma unroll
    for (int q = 0; q < 4; ++q) {
        int key = i0 + q;
        int node = base_node + (key >> QBITS);
        if (node < N_NODES) {
            off4[(size_t)base_node * 4 + key] = run;
            if (node == N_NODES - 1 && (key & 3) == 3)
                off4[(size_t)N_NODES * 4] = run + vals[q];
        }
        lh[key] = run;
        run += vals[q];
    }
    __syncthreads();

    for (int i = t; i < nv; i += 512) {
        uint4 p = p4[i];
#pragma unroll
        for (int q = 0; q < 4; ++q) {
            unsigned int pe = (q == 0) ? p.x : (q == 1) ? p.y : (q == 2) ? p.z : p.w;
            int key = (int)(((pe & (BKT_SIZE - 1)) << QBITS) | (pe >> 26));
            int sidx = (int)(pe >> BKT_BITS);
            int pos = atomicAdd(&lh[key], 1);
            stage[pos - cstart] = sidx;
            atomicAdd(&laccum[pe & (BKT_SIZE - 1)], xfeat[sidx]);
        }
    }
    if (t < (count & 3)) {
        unsigned int pe = pairs2[pstart + (nv << 2) + t];
        int key = (int)(((pe & (BKT_SIZE - 1)) << QBITS) | (pe >> 26));
        int sidx = (int)(pe >> BKT_BITS);
        int pos = atomicAdd(&lh[key], 1);
        stage[pos - cstart] = sidx;
        atomicAdd(&laccum[pe & (BKT_SIZE - 1)], xfeat[sidx]);
    }
    __syncthreads();

    for (int j = t; j < count; j += 512)
        __builtin_nontemporal_store(stage[j], &sorted_src[cstart + j]);
    int node = base_node + t;
    if (node < N_NODES) __builtin_nontemporal_store(laccum[t], &agg1[node]);
}

// ---------------------------------------------------------------------------
// transform1: h1 = relu(agg1*Wrel + brel + x*Wroot)   [1 -> 4], h1 fp16
// ---------------------------------------------------------------------------
__global__ __launch_bounds__(256) void transform1_kernel(
    const float* __restrict__ agg1, const float* __restrict__ x,
    const float* __restrict__ Wrel, const float* __restrict__ brel,
    const float* __restrict__ Wroot,
    __half2* __restrict__ h1)
{
    __shared__ float w[12];
    if (threadIdx.x < 4) {
        w[threadIdx.x] = Wrel[threadIdx.x];
        w[4 + threadIdx.x] = brel[threadIdx.x];
        w[8 + threadIdx.x] = Wroot[threadIdx.x];
    }
    __syncthreads();
    int i = blockIdx.x * blockDim.x + threadIdx.x;
    if (i >= N_NODES) return;
    float a = agg1[i], xv = x[i];
    float r0 = fmaxf(a * w[0] + w[4] + xv * w[8],  0.0f);
    float r1 = fmaxf(a * w[1] + w[5] + xv * w[9],  0.0f);
    float r2 = fmaxf(a * w[2] + w[6] + xv * w[10], 0.0f);
    float r3 = fmaxf(a * w[3] + w[7] + xv * w[11], 0.0f);
    u32x2 v = { h2u(__floats2half2_rn(r0, r1)), h2u(__floats2half2_rn(r2, r3)) };
    __builtin_nontemporal_store(v, (u32x2*)(h1 + (size_t)i * 2));
}

// ---------------------------------------------------------------------------
// Fused gather+transform, layer 2 (2 lanes/node, LDS tile). off4 stride-4.
// ---------------------------------------------------------------------------
__global__ __launch_bounds__(256) void gather2t_kernel(
    const int* __restrict__ off4, const int* __restrict__ ss,
    const __half2* __restrict__ h1,
    const float* __restrict__ Wrel, const float* __restrict__ brel,
    const float* __restrict__ Wroot,
    __half2* __restrict__ h2)
{
    __shared__ float tile[128 * 5];
    __shared__ float sWr[28], sWo[28], sb[7];
    int t = threadIdx.x;
    if (t < 28) { sWr[t] = Wrel[t]; sWo[t] = Wroot[t]; }
    if (t < 7) sb[t] = brel[t];

    int ln = t >> 1;
    int j = t & 1;
    int node = blockIdx.x * 128 + ln;
    if (node < N_NODES) {
        int start = off4[(size_t)node * 4], end = off4[(size_t)node * 4 + 4];
        float a0x=0,a0y=0,a1x=0,a1y=0,a2x=0,a2y=0,a3x=0,a3y=0;
        float b0x=0,b0y=0,b1x=0,b1y=0,b2x=0,b2y=0,b3x=0,b3y=0;
        int e = start;
        for (; e + 8 <= end; e += 8) {
            int s0=ss[e],s1=ss[e+1],s2=ss[e+2],s3=ss[e+3];
            int s4=ss[e+4],s5=ss[e+5],s6=ss[e+6],s7=ss[e+7];
            float2 f0=__half22float2(h1[(size_t)s0*2+j]);
            float2 f1=__half22float2(h1[(size_t)s1*2+j]);
            float2 f2=__half22float2(h1[(size_t)s2*2+j]);
            float2 f3=__half22float2(h1[(size_t)s3*2+j]);
            float2 f4=__half22float2(h1[(size_t)s4*2+j]);
            float2 f5=__half22float2(h1[(size_t)s5*2+j]);
            float2 f6=__half22float2(h1[(size_t)s6*2+j]);
            float2 f7=__half22float2(h1[(size_t)s7*2+j]);
            a0x+=f0.x;a0y+=f0.y; a1x+=f1.x;a1y+=f1.y;
            a2x+=f2.x;a2y+=f2.y; a3x+=f3.x;a3y+=f3.y;
            b0x+=f4.x;b0y+=f4.y; b1x+=f5.x;b1y+=f5.y;
            b2x+=f6.x;b2y+=f6.y; b3x+=f7.x;b3y+=f7.y;
        }
        for (; e < end; ++e) {
            float2 f = __half22float2(h1[(size_t)ss[e]*2+j]);
            a0x += f.x; a0y += f.y;
        }
        float rx = ((a0x+a1x)+(a2x+a3x)) + ((b0x+b1x)+(b2x+b3x));
        float ry = ((a0y+a1y)+(a2y+a3y)) + ((b0y+b1y)+(b2y+b3y));
        tile[ln * 5 + 2 * j] = rx;
        tile[ln * 5 + 2 * j + 1] = ry;
    }
    __syncthreads();

    if (t < 128) {
        int n2 = blockIdx.x * 128 + t;
        if (n2 < N_NODES) {
            float av[4];
#pragma unroll
            for (int k = 0; k < 4; ++k) av[k] = tile[t * 5 + k];
            float2 x01 = __half22float2(h1[(size_t)n2 * 2]);
            float2 x23 = __half22float2(h1[(size_t)n2 * 2 + 1]);
            float xv[4] = {x01.x, x01.y, x23.x, x23.y};
            float o_[8];
#pragma unroll
            for (int o = 0; o < 7; ++o) {
                float v = sb[o];
#pragma unroll
                for (int k = 0; k < 4; ++k)
                    v += av[k] * sWr[k * 7 + o] + xv[k] * sWo[k * 7 + o];
                o_[o] = fmaxf(v, 0.0f);
            }
            o_[7] = 0.0f;
            u32x4 v = { h2u(__floats2half2_rn(o_[0], o_[1])),
                        h2u(__floats2half2_rn(o_[2], o_[3])),
                        h2u(__floats2half2_rn(o_[4], o_[5])),
                        h2u(__floats2half2_rn(o_[6], o_[7])) };
            __builtin_nontemporal_store(v, (u32x4*)(h2 + (size_t)n2 * 4));
        }
    }
}

// ---------------------------------------------------------------------------
// Layer-3 gather, cache-blocked: pass Q touches only h2 quartile (2MB slice).
// 4 lanes/node, 16-deep unroll. Pass 0 nt-stores agg (stride 8); 1-3 RMW.
// ---------------------------------------------------------------------------
template<int Q>
__global__ __launch_bounds__(256) void gather3_kernel(
    const int* __restrict__ off4, const int* __restrict__ ss,
    const __half2* __restrict__ h2, float* __restrict__ agg)
{
    int node = blockIdx.x * 64 + (threadIdx.x >> 2);
    int j = threadIdx.x & 3;
    if (node >= N_NODES) return;
    int start = off4[(size_t)node * 4 + Q], end = off4[(size_t)node * 4 + Q + 1];

    float a0x=0,a0y=0,a1x=0,a1y=0,a2x=0,a2y=0,a3x=0,a3y=0;
    float b0x=0,b0y=0,b1x=0,b1y=0,b2x=0,b2y=0,b3x=0,b3y=0;
    int e = start;
    for (; e + 16 <= end; e += 16) {
        int s0=ss[e+0], s1=ss[e+1], s2=ss[e+2],  s3=ss[e+3];
        int s4=ss[e+4], s5=ss[e+5], s6=ss[e+6],  s7=ss[e+7];
        int s8=ss[e+8], s9=ss[e+9], sa=ss[e+10], sb=ss[e+11];
        int sc=ss[e+12],sd=ss[e+13],se=ss[e+14], sf=ss[e+15];
        float2 f0=__half22float2(h2[(size_t)s0*4+j]);
        float2 f1=__half22float2(h2[(size_t)s1*4+j]);
        float2 f2=__half22float2(h2[(size_t)s2*4+j]);
        float2 f3=__half22float2(h2[(size_t)s3*4+j]);
        float2 f4=__half22float2(h2[(size_t)s4*4+j]);
        float2 f5=__half22float2(h2[(size_t)s5*4+j]);
        float2 f6=__half22float2(h2[(size_t)s6*4+j]);
        float2 f7=__half22float2(h2[(size_t)s7*4+j]);
        float2 f8=__half22float2(h2[(size_t)s8*4+j]);
        float2 f9=__half22float2(h2[(size_t)s9*4+j]);
        float2 fa=__half22float2(h2[(size_t)sa*4+j]);
        float2 fb=__half22float2(h2[(size_t)sb*4+j]);
        float2 fc=__half22float2(h2[(size_t)sc*4+j]);
        float2 fd=__half22float2(h2[(size_t)sd*4+j]);
        float2 fe=__half22float2(h2[(size_t)se*4+j]);
        float2 ff=__half22float2(h2[(size_t)sf*4+j]);
        a0x+=f0.x;a0y+=f0.y; a1x+=f1.x;a1y+=f1.y;
        a2x+=f2.x;a2y+=f2.y; a3x+=f3.x;a3y+=f3.y;
        b0x+=f4.x;b0y+=f4.y; b1x+=f5.x;b1y+=f5.y;
        b2x+=f6.x;b2y+=f6.y; b3x+=f7.x;b3y+=f7.y;
        a0x+=f8.x;a0y+=f8.y; a1x+=f9.x;a1y+=f9.y;
        a2x+=fa.x;a2y+=fa.y; a3x+=fb.x;a3y+=fb.y;
        b0x+=fc.x;b0y+=fc.y; b1x+=fd.x;b1y+=fd.y;
        b2x+=fe.x;b2y+=fe.y; b3x+=ff.x;b3y+=ff.y;
    }
    for (; e + 4 <= end; e += 4) {
        int s0=ss[e+0], s1=ss[e+1], s2=ss[e+2], s3=ss[e+3];
        float2 f0=__half22float2(h2[(size_t)s0*4+j]);
        float2 f1=__half22float2(h2[(size_t)s1*4+j]);
        float2 f2=__half22float2(h2[(size_t)s2*4+j]);
        float2 f3=__half22float2(h2[(size_t)s3*4+j]);
        a0x+=f0.x;a0y+=f0.y; a1x+=f1.x;a1y+=f1.y;
        a2x+=f2.x;a2y+=f2.y; a3x+=f3.x;a3y+=f3.y;
    }
    for (; e < end; ++e) {
        float2 f = __half22float2(h2[(size_t)ss[e]*4+j]);
        a0x += f.x; a0y += f.y;
    }
    float rx = ((a0x+a1x)+(a2x+a3x)) + ((b0x+b1x)+(b2x+b3x));
    float ry = ((a0y+a1y)+(a2y+a3y)) + ((b0y+b1y)+(b2y+b3y));
    float* dst = agg + (size_t)node * 8 + j * 2;
    if (Q == 0) {
        f32x2 v = { rx, ry };
        __builtin_nontemporal_store(v, (f32x2*)dst);
    } else {
        f32x2 v = *(const f32x2*)dst;
        v[0] += rx; v[1] += ry;
        __builtin_nontemporal_store(v, (f32x2*)dst);
    }
}

// ---------------------------------------------------------------------------
// transform3: h3 = relu(agg@Wrel + brel + h2@Wroot)  [7 -> 10], streams
// agg (stride 8) + h2; writes h3 (32B rows, pads 0).
// ---------------------------------------------------------------------------
__global__ __launch_bounds__(256) void transform3_kernel(
    const float* __restrict__ agg, const __half2* __restrict__ h2,
    const float* __restrict__ Wrel, const float* __restrict__ brel,
    const float* __restrict__ Wroot,
    __half2* __restrict__ h3)
{
    __shared__ float sWr[70], sWo[70], sb[10];
    int t = threadIdx.x;
    if (t < 70) { sWr[t] = Wrel[t]; sWo[t] = Wroot[t]; }
    if (t < 10) sb[t] = brel[t];
    __syncthreads();
    int i = blockIdx.x * blockDim.x + threadIdx.x;
    if (i >= N_NODES) return;
    const float4* ap = (const float4*)(agg + (size_t)i * 8);
    float4 a0 = ap[0], a1 = ap[1];
    float av[7] = {a0.x, a0.y, a0.z, a0.w, a1.x, a1.y, a1.z};
    float xv[8];
#pragma unroll
    for (int q = 0; q < 4; ++q) {
        float2 f = __half22float2(h2[(size_t)i * 4 + q]);
        xv[2 * q] = f.x; xv[2 * q + 1] = f.y;
    }
    float o_[16];
#pragma unroll
    for (int o = 0; o < 10; ++o) {
        float v = sb[o];
#pragma unroll
        for (int k = 0; k < 7; ++k)
            v += av[k] * sWr[k * 10 + o] + xv[k] * sWo[k * 10 + o];
        o_[o] = fmaxf(v, 0.0f);
    }
#pragma unroll
    for (int o = 10; o < 16; ++o) o_[o] = 0.0f;
    u32x4 v0 = { h2u(__floats2half2_rn(o_[0], o_[1])),
                 h2u(__floats2half2_rn(o_[2], o_[3])),
                 h2u(__floats2half2_rn(o_[4], o_[5])),
                 h2u(__floats2half2_rn(o_[6], o_[7])) };
    u32x4 v1 = { h2u(__floats2half2_rn(o_[8], o_[9])),
                 h2u(__floats2half2_rn(o_[10], o_[11])),
                 h2u(__floats2half2_rn(o_[12], o_[13])),
                 h2u(__floats2half2_rn(o_[14], o_[15])) };
    __builtin_nontemporal_store(v0, (u32x4*)(h3 + (size_t)i * 8));
    __builtin_nontemporal_store(v1, (u32x4*)(h3 + (size_t)i * 8 + 4));
}

// ---------------------------------------------------------------------------
// Layer-4 gather, cache-blocked: pass Q touches only h3 quartile (4MB slice).
// 8 lanes/node, 16-deep unroll. Pass 0 nt-stores agg (stride 16); 1-3 RMW.
// ---------------------------------------------------------------------------
template<int Q>
__global__ __launch_bounds__(256) void gather4_kernel(
    const int* __restrict__ off4, const int* __restrict__ ss,
    const __half2* __restrict__ h3, float* __restrict__ agg)
{
    int node = blockIdx.x * 32 + (threadIdx.x >> 3);
    int j = threadIdx.x & 7;
    if (node >= N_NODES) return;
    int start = off4[(size_t)node * 4 + Q], end = off4[(size_t)node * 4 + Q + 1];

    float a0x=0,a0y=0,a1x=0,a1y=0,a2x=0,a2y=0,a3x=0,a3y=0;
    float b0x=0,b0y=0,b1x=0,b1y=0,b2x=0,b2y=0,b3x=0,b3y=0;
    int e = start;
    for (; e + 16 <= end; e += 16) {
        int s0=ss[e+0], s1=ss[e+1], s2=ss[e+2],  s3=ss[e+3];
        int s4=ss[e+4], s5=ss[e+5], s6=ss[e+6],  s7=ss[e+7];
        int s8=ss[e+8], s9=ss[e+9], sa=ss[e+10], sb=ss[e+11];
        int sc=ss[e+12],sd=ss[e+13],se=ss[e+14], sf=ss[e+15];
        float2 f0=__half22float2(h3[(size_t)s0*8+j]);
        float2 f1=__half22float2(h3[(size_t)s1*8+j]);
        float2 f2=__half22float2(h3[(size_t)s2*8+j]);
        float2 f3=__half22float2(h3[(size_t)s3*8+j]);
        float2 f4=__half22float2(h3[(size_t)s4*8+j]);
        float2 f5=__half22float2(h3[(size_t)s5*8+j]);
        float2 f6=__half22float2(h3[(size_t)s6*8+j]);
        float2 f7=__half22float2(h3[(size_t)s7*8+j]);
        float2 f8=__half22float2(h3[(size_t)s8*8+j]);
        float2 f9=__half22float2(h3[(size_t)s9*8+j]);
        float2 fa=__half22float2(h3[(size_t)sa*8+j]);
        float2 fb=__half22float2(h3[(size_t)sb*8+j]);
        float2 fc=__half22float2(h3[(size_t)sc*8+j]);
        float2 fd=__half22float2(h3[(size_t)sd*8+j]);
        float2 fe=__half22float2(h3[(size_t)se*8+j]);
        float2 ff=__half22float2(h3[(size_t)sf*8+j]);
        a0x+=f0.x;a0y+=f0.y; a1x+=f1.x;a1y+=f1.y;
        a2x+=f2.x;a2y+=f2.y; a3x+=f3.x;a3y+=f3.y;
        b0x+=f4.x;b0y+=f4.y; b1x+=f5.x;b1y+=f5.y;
        b2x+=f6.x;b2y+=f6.y; b3x+=f7.x;b3y+=f7.y;
        a0x+=f8.x;a0y+=f8.y; a1x+=f9.x;a1y+=f9.y;
        a2x+=fa.x;a2y+=fa.y; a3x+=fb.x;a3y+=fb.y;
        b0x+=fc.x;b0y+=fc.y; b1x+=fd.x;b1y+=fd.y;
        b2x+=fe.x;b2y+=fe.y; b3x+=ff.x;b3y+=ff.y;
    }
    for (; e + 4 <= end; e += 4) {
        int s0=ss[e+0], s1=ss[e+1], s2=ss[e+2], s3=ss[e+3];
        float2 f0=__half22float2(h3[(size_t)s0*8+j]);
        float2 f1=__half22float2(h3[(size_t)s1*8+j]);
        float2 f2=__half22float2(h3[(size_t)s2*8+j]);
        float2 f3=__half22float2(h3[(size_t)s3*8+j]);
        a0x+=f0.x;a0y+=f0.y; a1x+=f1.x;a1y+=f1.y;
        a2x+=f2.x;a2y+=f2.y; a3x+=f3.x;a3y+=f3.y;
    }
    for (; e < end; ++e) {
        float2 f = __half22float2(h3[(size_t)ss[e]*8+j]);
        a0x += f.x; a0y += f.y;
    }
    float rx = ((a0x+a1x)+(a2x+a3x)) + ((b0x+b1x)+(b2x+b3x));
    float ry = ((a0y+a1y)+(a2y+a3y)) + ((b0y+b1y)+(b2y+b3y));
    float* dst = agg + (size_t)node * 16 + j * 2;
    if (Q == 0) {
        f32x2 v = { rx, ry };
        __builtin_nontemporal_store(v, (f32x2*)dst);
    } else {
        f32x2 v = *(const f32x2*)dst;
        v[0] += rx; v[1] += ry;
        __builtin_nontemporal_store(v, (f32x2*)dst);
    }
}

// ---------------------------------------------------------------------------
// layer4 transform + 3-layer MLP (separate kernel; streams agg + h3).
// ---------------------------------------------------------------------------
__global__ __launch_bounds__(256) void layer4_mlp_kernel(
    const float* __restrict__ agg, const __half2* __restrict__ h3,
    const float* __restrict__ g4Wrel, const float* __restrict__ g4brel,
    const float* __restrict__ g4Wroot,
    const float* __restrict__ fc1W, const float* __restrict__ fc1b,
    const float* __restrict__ fc2W, const float* __restrict__ fc2b,
    const float* __restrict__ fc3W, const float* __restrict__ fc3b,
    float* __restrict__ out)
{
    __shared__ float s[1680];
    float* sWrel  = s;            // 160
    float* sbrel  = s + 160;      // 16
    float* sWroot = s + 176;      // 160
    float* sfc1W  = s + 336;      // 512
    float* sfc1b  = s + 848;      // 32
    float* sfc2W  = s + 880;      // 512
    float* sfc2b  = s + 1392;     // 16
    float* sfc3W  = s + 1408;     // 256
    float* sfc3b  = s + 1664;     // 16
    int t = threadIdx.x;
    for (int i = t; i < 160; i += 256) { sWrel[i] = g4Wrel[i]; sWroot[i] = g4Wroot[i]; }
    for (int i = t; i < 512; i += 256) { sfc1W[i] = fc1W[i]; sfc2W[i] = fc2W[i]; }
    if (t < 256) sfc3W[t] = fc3W[t];
    if (t < 32)  sfc1b[t] = fc1b[t];
    if (t < 16)  { sbrel[t] = g4brel[t]; sfc2b[t] = fc2b[t]; sfc3b[t] = fc3b[t]; }
    __syncthreads();

    int i = blockIdx.x * blockDim.x + threadIdx.x;
    if (i >= N_NODES) return;

    const float4* ap = (const float4*)(agg + (size_t)i * 16);
    float4 a0 = ap[0], a1 = ap[1], a2 = ap[2];
    float a[10] = {a0.x, a0.y, a0.z, a0.w, a1.x, a1.y, a1.z, a1.w, a2.x, a2.y};
    float xin[10];
#pragma unroll
    for (int q = 0; q < 5; ++q) {
        float2 f = __half22float2(h3[(size_t)i * 8 + q]);
        xin[2 * q] = f.x; xin[2 * q + 1] = f.y;
    }

    float h4[16];
#pragma unroll
    for (int o = 0; o < 16; ++o) {
        float v = sbrel[o];
#pragma unroll
        for (int k = 0; k < 10; ++k)
            v += a[k] * sWrel[k * 16 + o] + xin[k] * sWroot[k * 16 + o];
        h4[o] = fmaxf(v, 0.0f);
    }
    float m1[32];
#pragma unroll
    for (int o = 0; o < 32; ++o) {
        float v = sfc1b[o];
#pragma unroll
        for (int k = 0; k < 16; ++k) v += h4[k] * sfc1W[k * 32 + o];
        m1[o] = fmaxf(v, 0.0f);
    }
    float m2[16];
#pragma unroll
    for (int o = 0; o < 16; ++o) {
        float v = sfc2b[o];
#pragma unroll
        for (int k = 0; k < 32; ++k) v += m1[k] * sfc2W[k * 16 + o];
        m2[o] = fmaxf(v, 0.0f);
    }
    float r[16];
#pragma unroll
    for (int o = 0; o < 16; ++o) {
        float v = sfc3b[o];
#pragma unroll
        for (int k = 0; k < 16; ++k) v += m2[k] * sfc3W[k * 16 + o];
        r[o] = v;
    }
#pragma unroll
    for (int q = 0; q < 4; ++q) {
        f32x4 v = { r[q*4+0], r[q*4+1], r[q*4+2], r[q*4+3] };
        __builtin_nontemporal_store(v, (f32x4*)(out + (size_t)i * 16 + q * 4));
    }
}

// ---------------------------------------------------------------------------
extern "C" void kernel_launch(void* const* d_in, const int* in_sizes, int n_in,
                              void* d_out, int out_size, void* d_ws, size_t ws_size,
                              hipStream_t stream) {
    const float* x        = (const float*)d_in[0];
    const int*   ei       = (const int*)d_in[1];
    const float* g1_Wrel  = (const float*)d_in[2];
    const float* g1_brel  = (const float*)d_in[3];
    const float* g1_Wroot = (const float*)d_in[4];
    const float* g2_Wrel  = (const float*)d_in[5];
    const float* g2_brel  = (const float*)d_in[6];
    const float* g2_Wroot = (const float*)d_in[7];
    const float* g3_Wrel  = (const float*)d_in[8];
    const float* g3_brel  = (const float*)d_in[9];
    const float* g3_Wroot = (const float*)d_in[10];
    const float* g4_Wrel  = (const float*)d_in[11];
    const float* g4_brel  = (const float*)d_in[12];
    const float* g4_Wroot = (const float*)d_in[13];
    const float* fc1_W    = (const float*)d_in[14];
    const float* fc1_b    = (const float*)d_in[15];
    const float* fc2_W    = (const float*)d_in[16];
    const float* fc2_b    = (const float*)d_in[17];
    const float* fc3_W    = (const float*)d_in[18];
    const float* fc3_b    = (const float*)d_in[19];
    float* out = (float*)d_out;

    const int* srcp = ei;
    const int* dstp = ei + N_EDGES;

    // ---- workspace layout (256B aligned), ~148 MiB ----
    char* p = (char*)d_ws;
    auto alloc = [&](size_t bytes) {
        char* r = p;
        p += (bytes + 255) & ~(size_t)255;
        return r;
    };
    // region A: h1+h2+h3+agg+pad (74 MiB), aliased by pairs2 (64.9 MiB).
    __half2* h1  = (__half2*)alloc((size_t)N_NODES * 2 * sizeof(__half2));  //  4 MB
    __half2* h2  = (__half2*)alloc((size_t)N_NODES * 4 * sizeof(__half2));  //  8 MB
    __half2* h3  = (__half2*)alloc((size_t)N_NODES * 8 * sizeof(__half2));  // 16 MB
    float*   agg = (float*)  alloc((size_t)N_NODES * 16 * 4);               // 32 MB
    alloc((size_t)14 * 1024 * 1024);                                        // pad
    unsigned int* pairs2 = (unsigned int*)h1;          // 977*17408*4 = 64.9 MiB
    // region B: pairs1 (bin1 out / bin2 in), reused as sorted_src after bin2.
    int* sorted_src = (int*)alloc((size_t)NSUPER * CAP1 * 4);  // 63.9 MiB
    unsigned int* pairs1 = (unsigned int*)sorted_src;
    int*   off4  = (int*)alloc(((size_t)N_NODES * 4 + 1) * 4); //  8 MB
    float* agg1  = (float*)alloc((size_t)N_NODES * 4);         //  2 MB
    int*   bcur1 = (int*)alloc((size_t)NSUPER * 4);
    int*   bcur2 = (int*)alloc((size_t)NBUCKET * 4);
    int*   bbase = (int*)alloc((size_t)(NBUCKET + 1) * 4);

    const int TB = 256;
    const int node_blocks = (N_NODES + TB - 1) / TB;

    // ---- CSR build: bin1 -> bin2 -> scan -> staged single-pass sort ----
    init_bcur_kernel<<<2, 512, 0, stream>>>(bcur1, bcur2);
    bin1_kernel<<<B1_NBLK, 256, 0, stream>>>(srcp, dstp, bcur1, pairs1);
    bin2_kernel<<<NSUPER * B2_PER_SUPER, 256, 0, stream>>>(bcur1, bcur2, pairs1, pairs2);
    bucket_scan_kernel<<<1, 512, 0, stream>>>(bcur2, bbase);
    bucket_sort512_kernel<<<NBUCKET, 512, 0, stream>>>(
        bcur2, bbase, pairs2, x, off4, sorted_src, agg1);

    // ---- layer 1: transform only (agg fused in sort); h1 fp16 ----
    transform1_kernel<<<node_blocks, TB, 0, stream>>>(
        agg1, x, g1_Wrel, g1_brel, g1_Wroot, h1);

    // ---- layer 2: fused gather+transform ----
    gather2t_kernel<<<(N_NODES + 127) / 128, TB, 0, stream>>>(
        off4, sorted_src, h1, g2_Wrel, g2_brel, g2_Wroot, h2);

    // ---- layer 3: 4 cache-blocked gather passes (2MB h2 slices) + transform ----
    const int g3_blocks = (N_NODES + 63) / 64;
    gather3_kernel<0><<<g3_blocks, TB, 0, stream>>>(off4, sorted_src, h2, agg);
    gather3_kernel<1><<<g3_blocks, TB, 0, stream>>>(off4, sorted_src, h2, agg);
    gather3_kernel<2><<<g3_blocks, TB, 0, stream>>>(off4, sorted_src, h2, agg);
    gather3_kernel<3><<<g3_blocks, TB, 0, stream>>>(off4, sorted_src, h2, agg);
    transform3_kernel<<<node_blocks, TB, 0, stream>>>(
        agg, h2, g3_Wrel, g3_brel, g3_Wroot, h3);

    // ---- layer 4: 4 cache-blocked gather passes, then transform+MLP ----
    const int g4_blocks = (N_NODES + 31) / 32;
    gather4_kernel<0><<<g4_blocks, TB, 0, stream>>>(off4, sorted_src, h3, agg);
    gather4_kernel<1><<<g4_blocks, TB, 0, stream>>>(off4, sorted_src, h3, agg);
    gather4_kernel<2><<<g4_blocks, TB, 0, stream>>>(off4, sorted_src, h3, agg);
    gather4_kernel<3><<<g4_blocks, TB, 0, stream>>>(off4, sorted_src, h3, agg);
    layer4_mlp_kernel<<<node_blocks, TB, 0, stream>>>(
        agg, h3, g4_Wrel, g4_brel, g4_Wroot,
        fc1_W, fc1_b, fc2_W, fc2_b, fc3_W, fc3_b, out);
}

// Round 20
// 834.190 us; speedup vs baseline: 1.0641x; 1.0641x over previous
//
#include <hip/hip_runtime.h>
#include <hip/hip_fp16.h>

#define N_NODES 500000
#define N_EDGES 16000000

// level-1: super-buckets of 8192 dst nodes
#define SB_BITS 13
#define SB_SIZE (1 << SB_BITS)                               // 8192
#define NSUPER ((N_NODES + SB_SIZE - 1) / SB_SIZE)           // 62
#define CAP1 270336                                          // mean 262144 + 16 sigma
// level-2: buckets of 512 dst nodes
#define BKT_BITS 9
#define BKT_SIZE (1 << BKT_BITS)                             // 512
#define NBUCKET ((N_NODES + BKT_SIZE - 1) / BKT_SIZE)        // 977
#define BKT_CAP 17408                                        // mean 16376 + 8 sigma (68KB stage)
// src-quartile sub-key (4 x 131072-node ranges)
#define QBITS 2
#define NKEY (BKT_SIZE << QBITS)                             // 2048
// bin1 geometry (977 blocks, ~4/CU)
#define B1_EPT 64
#define B1_CHUNK (256 * B1_EPT)                              // 16384 edges
#define B1_NBLK ((N_EDGES + B1_CHUNK - 1) / B1_CHUNK)        // 977
#define B1_VQ (B1_EPT / 4)                                   // 16 int4/thread
#define NV4 (N_EDGES / 4)
// bin2 geometry (992 blocks)
#define B2_PER_SUPER 16

typedef unsigned int u32x2 __attribute__((ext_vector_type(2)));
typedef unsigned int u32x4 __attribute__((ext_vector_type(4)));
typedef float f32x2 __attribute__((ext_vector_type(2)));
typedef float f32x4 __attribute__((ext_vector_type(4)));

__device__ __forceinline__ unsigned int h2u(__half2 h) { return *(unsigned int*)&h; }
__device__ __forceinline__ float2 u2f2(unsigned int u) { return __half22float2(*(__half2*)&u); }

// ---------------------------------------------------------------------------
__global__ __launch_bounds__(512) void init_bcur_kernel(
    int* __restrict__ bcur1, int* __restrict__ bcur2)
{
    int i = blockIdx.x * 512 + threadIdx.x;
    if (i < NSUPER) bcur1[i] = i * CAP1;
    if (i < NBUCKET) bcur2[i] = i * BKT_CAP;
}

// ---------------------------------------------------------------------------
// bin1: edges -> 62 super-bucket regions. pairs1[pos] = (src<<13)|(dst&8191).
// ---------------------------------------------------------------------------
__global__ __launch_bounds__(256) void bin1_kernel(
    const int* __restrict__ src, const int* __restrict__ dst,
    int* __restrict__ bcur1, unsigned int* __restrict__ pairs1)
{
    __shared__ int lh[NSUPER];
    __shared__ int lbase[NSUPER];
    const int4* dst4 = (const int4*)dst;
    const int4* src4 = (const int4*)src;
    int t = threadIdx.x;
    long v0 = (long)blockIdx.x * (B1_CHUNK / 4);

    if (t < NSUPER) lh[t] = 0;
    __syncthreads();

#pragma unroll 4
    for (int q = 0; q < B1_VQ; ++q) {
        long v = v0 + q * 256 + t;
        if (v < NV4) {
            int4 d = dst4[v];
            atomicAdd(&lh[d.x >> SB_BITS], 1);
            atomicAdd(&lh[d.y >> SB_BITS], 1);
            atomicAdd(&lh[d.z >> SB_BITS], 1);
            atomicAdd(&lh[d.w >> SB_BITS], 1);
        }
    }
    __syncthreads();

    if (t < NSUPER) {
        int c = lh[t];
        lbase[t] = c ? atomicAdd(&bcur1[t], c) : 0;
        lh[t] = 0;   // reuse as running counter
    }
    __syncthreads();

#pragma unroll 4
    for (int q = 0; q < B1_VQ; ++q) {
        long v = v0 + q * 256 + t;
        if (v < NV4) {
            int4 d = dst4[v];
            int4 s = src4[v];
            {
                int b = d.x >> SB_BITS;
                int r = atomicAdd(&lh[b], 1);
                pairs1[lbase[b] + r] = ((unsigned int)s.x << SB_BITS) | (unsigned int)(d.x & (SB_SIZE - 1));
            }
            {
                int b = d.y >> SB_BITS;
                int r = atomicAdd(&lh[b], 1);
                pairs1[lbase[b] + r] = ((unsigned int)s.y << SB_BITS) | (unsigned int)(d.y & (SB_SIZE - 1));
            }
            {
                int b = d.z >> SB_BITS;
                int r = atomicAdd(&lh[b], 1);
                pairs1[lbase[b] + r] = ((unsigned int)s.z << SB_BITS) | (unsigned int)(d.z & (SB_SIZE - 1));
            }
            {
                int b = d.w >> SB_BITS;
                int r = atomicAdd(&lh[b], 1);
                pairs1[lbase[b] + r] = ((unsigned int)s.w << SB_BITS) | (unsigned int)(d.w & (SB_SIZE - 1));
            }
        }
    }
}

// ---------------------------------------------------------------------------
// bin2: 16 blocks per super; contiguous slice of pairs1 -> 16 sub-buckets.
// pairs2[pos] = (src<<9)|(dst&511).
// ---------------------------------------------------------------------------
__global__ __launch_bounds__(256) void bin2_kernel(
    const int* __restrict__ bcur1, int* __restrict__ bcur2,
    const unsigned int* __restrict__ pairs1, unsigned int* __restrict__ pairs2)
{
    __shared__ int lh[16];
    __shared__ int lbase[16];
    int s = blockIdx.x >> 4;
    int blk = blockIdx.x & 15;
    int t = threadIdx.x;
    int count = bcur1[s] - s * CAP1;
    int chunk = (((count + B2_PER_SUPER - 1) / B2_PER_SUPER) + 3) & ~3;
    int lo = blk * chunk;
    int hi = lo + chunk; if (hi > count) hi = count;
    int len = hi > lo ? hi - lo : 0;
    const unsigned int* base = pairs1 + (size_t)s * CAP1 + lo;
    const uint4* p4 = (const uint4*)base;
    int nv = len >> 2;

    if (t < 16) lh[t] = 0;
    __syncthreads();

    for (int i = t; i < nv; i += 256) {
        uint4 p = p4[i];
        atomicAdd(&lh[(p.x & (SB_SIZE - 1)) >> BKT_BITS], 1);
        atomicAdd(&lh[(p.y & (SB_SIZE - 1)) >> BKT_BITS], 1);
        atomicAdd(&lh[(p.z & (SB_SIZE - 1)) >> BKT_BITS], 1);
        atomicAdd(&lh[(p.w & (SB_SIZE - 1)) >> BKT_BITS], 1);
    }
    if (t < (len & 3))
        atomicAdd(&lh[(base[(nv << 2) + t] & (SB_SIZE - 1)) >> BKT_BITS], 1);
    __syncthreads();

    if (t < 16) {
        int c = lh[t];
        lbase[t] = c ? atomicAdd(&bcur2[(s << 4) | t], c) : 0;
        lh[t] = 0;
    }
    __syncthreads();

    for (int i = t; i < nv; i += 256) {
        uint4 p = p4[i];
#pragma unroll
        for (int q = 0; q < 4; ++q) {
            unsigned int e = (q == 0) ? p.x : (q == 1) ? p.y : (q == 2) ? p.z : p.w;
            int sub = (int)((e & (SB_SIZE - 1)) >> BKT_BITS);
            int r = atomicAdd(&lh[sub], 1);
            pairs2[lbase[sub] + r] = ((e >> SB_BITS) << BKT_BITS) | (e & (BKT_SIZE - 1));
        }
    }
    if (t < (len & 3)) {
        unsigned int e = base[(nv << 2) + t];
        int sub = (int)((e & (SB_SIZE - 1)) >> BKT_BITS);
        int r = atomicAdd(&lh[sub], 1);
        pairs2[lbase[sub] + r] = ((e >> SB_BITS) << BKT_BITS) | (e & (BKT_SIZE - 1));
    }
}

// ---------------------------------------------------------------------------
__global__ __launch_bounds__(512) void bucket_scan_kernel(
    const int* __restrict__ bcur2, int* __restrict__ bbase)
{
    __shared__ int sdata[512];
    int t = threadIdx.x;
    int i0 = t * 2;
    int v0 = (i0 < NBUCKET) ? (bcur2[i0] - i0 * BKT_CAP) : 0;
    int v1 = (i0 + 1 < NBUCKET) ? (bcur2[i0 + 1] - (i0 + 1) * BKT_CAP) : 0;
    int s = v0 + v1;
    sdata[t] = s;
    __syncthreads();
    for (int o = 1; o < 512; o <<= 1) {
        int tmp = (t >= o) ? sdata[t - o] : 0;
        __syncthreads();
        sdata[t] += tmp;
        __syncthreads();
    }
    int run = sdata[t] - s;
    if (i0 < NBUCKET) bbase[i0] = run;
    if (i0 + 1 < NBUCKET) bbase[i0 + 1] = run + v0;
    if (i0 == NBUCKET - 1) bbase[NBUCKET] = run + v0;
    if (i0 + 1 == NBUCKET - 1) bbase[NBUCKET] = run + v0 + v1;
}

// ---------------------------------------------------------------------------
// One block (512 threads) per 512-node bucket. 2048-key histogram
// (key = (low9<<2)|src_quartile) + scan -> off4[node*4+q] + cursors; single
// placement pass into 68KB LDS stage; coalesced nt flush. Layer-1 agg fused.
// ---------------------------------------------------------------------------
__global__ __launch_bounds__(512) void bucket_sort512_kernel(
    const int* __restrict__ bcur2, const int* __restrict__ bbase,
    const unsigned int* __restrict__ pairs2, const float* __restrict__ xfeat,
    int* __restrict__ off4, int* __restrict__ sorted_src,
    float* __restrict__ agg1)
{
    __shared__ int   stage[BKT_CAP];     // 68 KB (scan scratch in [0..511] first)
    __shared__ int   lh[NKEY];           // 8 KB
    __shared__ float laccum[BKT_SIZE];   // 2 KB
    int b = blockIdx.x;
    int t = threadIdx.x;
    int base_node = b << BKT_BITS;
    size_t pstart = (size_t)b * BKT_CAP;
    int count = bcur2[b] - b * BKT_CAP;
    int cstart = bbase[b];

    lh[t] = 0; lh[512 + t] = 0; lh[1024 + t] = 0; lh[1536 + t] = 0;
    laccum[t & (BKT_SIZE - 1)] = 0.0f;
    __syncthreads();

    int nv = count >> 2;
    const uint4* p4 = (const uint4*)(pairs2 + pstart);
    for (int i = t; i < nv; i += 512) {
        uint4 p = p4[i];
        atomicAdd(&lh[((p.x & (BKT_SIZE - 1)) << QBITS) | (p.x >> 26)], 1);
        atomicAdd(&lh[((p.y & (BKT_SIZE - 1)) << QBITS) | (p.y >> 26)], 1);
        atomicAdd(&lh[((p.z & (BKT_SIZE - 1)) << QBITS) | (p.z >> 26)], 1);
        atomicAdd(&lh[((p.w & (BKT_SIZE - 1)) << QBITS) | (p.w >> 26)], 1);
    }
    if (t < (count & 3)) {
        unsigned int pe = pairs2[pstart + (nv << 2) + t];
        atomicAdd(&lh[((pe & (BKT_SIZE - 1)) << QBITS) | (pe >> 26)], 1);
    }
    __syncthreads();

    int i0 = t * 4;
    int c0 = lh[i0], c1 = lh[i0 + 1], c2 = lh[i0 + 2], c3 = lh[i0 + 3];
    int s = c0 + c1 + c2 + c3;
    stage[t] = s;
    __syncthreads();
    for (int o = 1; o < 512; o <<= 1) {
        int tmp = (t >= o) ? stage[t - o] : 0;
        __syncthreads();
        stage[t] += tmp;
        __syncthreads();
    }
    int run = cstart + stage[t] - s;
    int vals[4] = {c0, c1, c2, c3};
#pragma unroll
    for (int q = 0; q < 4; ++q) {
        int key = i0 + q;
        int node = base_node + (key >> QBITS);
        if (node < N_NODES) {
            off4[(size_t)base_node * 4 + key] = run;
            if (node == N_NODES - 1 && (key & 3) == 3)
                off4[(size_t)N_NODES * 4] = run + vals[q];
        }
        lh[key] = run;
        run += vals[q];
    }
    __syncthreads();

    for (int i = t; i < nv; i += 512) {
        uint4 p = p4[i];
#pragma unroll
        for (int q = 0; q < 4; ++q) {
            unsigned int pe = (q == 0) ? p.x : (q == 1) ? p.y : (q == 2) ? p.z : p.w;
            int key = (int)(((pe & (BKT_SIZE - 1)) << QBITS) | (pe >> 26));
            int sidx = (int)(pe >> BKT_BITS);
            int pos = atomicAdd(&lh[key], 1);
            stage[pos - cstart] = sidx;
            atomicAdd(&laccum[pe & (BKT_SIZE - 1)], xfeat[sidx]);
        }
    }
    if (t < (count & 3)) {
        unsigned int pe = pairs2[pstart + (nv << 2) + t];
        int key = (int)(((pe & (BKT_SIZE - 1)) << QBITS) | (pe >> 26));
        int sidx = (int)(pe >> BKT_BITS);
        int pos = atomicAdd(&lh[key], 1);
        stage[pos - cstart] = sidx;
        atomicAdd(&laccum[pe & (BKT_SIZE - 1)], xfeat[sidx]);
    }
    __syncthreads();

    for (int j = t; j < count; j += 512)
        __builtin_nontemporal_store(stage[j], &sorted_src[cstart + j]);
    int node = base_node + t;
    if (node < N_NODES) __builtin_nontemporal_store(laccum[t], &agg1[node]);
}

// ---------------------------------------------------------------------------
// transform1: h1 = relu(agg1*Wrel + brel + x*Wroot)   [1 -> 4], h1 fp16
// ---------------------------------------------------------------------------
__global__ __launch_bounds__(256) void transform1_kernel(
    const float* __restrict__ agg1, const float* __restrict__ x,
    const float* __restrict__ Wrel, const float* __restrict__ brel,
    const float* __restrict__ Wroot,
    __half2* __restrict__ h1)
{
    __shared__ float w[12];
    if (threadIdx.x < 4) {
        w[threadIdx.x] = Wrel[threadIdx.x];
        w[4 + threadIdx.x] = brel[threadIdx.x];
        w[8 + threadIdx.x] = Wroot[threadIdx.x];
    }
    __syncthreads();
    int i = blockIdx.x * blockDim.x + threadIdx.x;
    if (i >= N_NODES) return;
    float a = agg1[i], xv = x[i];
    float r0 = fmaxf(a * w[0] + w[4] + xv * w[8],  0.0f);
    float r1 = fmaxf(a * w[1] + w[5] + xv * w[9],  0.0f);
    float r2 = fmaxf(a * w[2] + w[6] + xv * w[10], 0.0f);
    float r3 = fmaxf(a * w[3] + w[7] + xv * w[11], 0.0f);
    u32x2 v = { h2u(__floats2half2_rn(r0, r1)), h2u(__floats2half2_rn(r2, r3)) };
    __builtin_nontemporal_store(v, (u32x2*)(h1 + (size_t)i * 2));
}

// ---------------------------------------------------------------------------
// Fused gather+transform, layer 2 (2 lanes/node, LDS tile). off4 stride-4.
// ---------------------------------------------------------------------------
__global__ __launch_bounds__(256) void gather2t_kernel(
    const int* __restrict__ off4, const int* __restrict__ ss,
    const __half2* __restrict__ h1,
    const float* __restrict__ Wrel, const float* __restrict__ brel,
    const float* __restrict__ Wroot,
    __half2* __restrict__ h2)
{
    __shared__ float tile[128 * 5];
    __shared__ float sWr[28], sWo[28], sb[7];
    int t = threadIdx.x;
    if (t < 28) { sWr[t] = Wrel[t]; sWo[t] = Wroot[t]; }
    if (t < 7) sb[t] = brel[t];

    int ln = t >> 1;
    int j = t & 1;
    int node = blockIdx.x * 128 + ln;
    if (node < N_NODES) {
        int start = off4[(size_t)node * 4], end = off4[(size_t)node * 4 + 4];
        float a0x=0,a0y=0,a1x=0,a1y=0,a2x=0,a2y=0,a3x=0,a3y=0;
        float b0x=0,b0y=0,b1x=0,b1y=0,b2x=0,b2y=0,b3x=0,b3y=0;
        int e = start;
        for (; e + 8 <= end; e += 8) {
            int s0=ss[e],s1=ss[e+1],s2=ss[e+2],s3=ss[e+3];
            int s4=ss[e+4],s5=ss[e+5],s6=ss[e+6],s7=ss[e+7];
            float2 f0=__half22float2(h1[(size_t)s0*2+j]);
            float2 f1=__half22float2(h1[(size_t)s1*2+j]);
            float2 f2=__half22float2(h1[(size_t)s2*2+j]);
            float2 f3=__half22float2(h1[(size_t)s3*2+j]);
            float2 f4=__half22float2(h1[(size_t)s4*2+j]);
            float2 f5=__half22float2(h1[(size_t)s5*2+j]);
            float2 f6=__half22float2(h1[(size_t)s6*2+j]);
            float2 f7=__half22float2(h1[(size_t)s7*2+j]);
            a0x+=f0.x;a0y+=f0.y; a1x+=f1.x;a1y+=f1.y;
            a2x+=f2.x;a2y+=f2.y; a3x+=f3.x;a3y+=f3.y;
            b0x+=f4.x;b0y+=f4.y; b1x+=f5.x;b1y+=f5.y;
            b2x+=f6.x;b2y+=f6.y; b3x+=f7.x;b3y+=f7.y;
        }
        for (; e < end; ++e) {
            float2 f = __half22float2(h1[(size_t)ss[e]*2+j]);
            a0x += f.x; a0y += f.y;
        }
        float rx = ((a0x+a1x)+(a2x+a3x)) + ((b0x+b1x)+(b2x+b3x));
        float ry = ((a0y+a1y)+(a2y+a3y)) + ((b0y+b1y)+(b2y+b3y));
        tile[ln * 5 + 2 * j] = rx;
        tile[ln * 5 + 2 * j + 1] = ry;
    }
    __syncthreads();

    if (t < 128) {
        int n2 = blockIdx.x * 128 + t;
        if (n2 < N_NODES) {
            float av[4];
#pragma unroll
            for (int k = 0; k < 4; ++k) av[k] = tile[t * 5 + k];
            float2 x01 = __half22float2(h1[(size_t)n2 * 2]);
            float2 x23 = __half22float2(h1[(size_t)n2 * 2 + 1]);
            float xv[4] = {x01.x, x01.y, x23.x, x23.y};
            float o_[8];
#pragma unroll
            for (int o = 0; o < 7; ++o) {
                float v = sb[o];
#pragma unroll
                for (int k = 0; k < 4; ++k)
                    v += av[k] * sWr[k * 7 + o] + xv[k] * sWo[k * 7 + o];
                o_[o] = fmaxf(v, 0.0f);
            }
            o_[7] = 0.0f;
            u32x4 v = { h2u(__floats2half2_rn(o_[0], o_[1])),
                        h2u(__floats2half2_rn(o_[2], o_[3])),
                        h2u(__floats2half2_rn(o_[4], o_[5])),
                        h2u(__floats2half2_rn(o_[6], o_[7])) };
            __builtin_nontemporal_store(v, (u32x4*)(h2 + (size_t)n2 * 4));
        }
    }
}

// ---------------------------------------------------------------------------
// Layer-3 gather, cache-blocked: pass Q touches only h2 quartile (2MB slice).
// 4 lanes/node, 16-deep unroll. Pass 0 nt-stores agg (stride 8); 1-3 RMW.
// ---------------------------------------------------------------------------
template<int Q>
__global__ __launch_bounds__(256) void gather3_kernel(
    const int* __restrict__ off4, const int* __restrict__ ss,
    const __half2* __restrict__ h2, float* __restrict__ agg)
{
    int node = blockIdx.x * 64 + (threadIdx.x >> 2);
    int j = threadIdx.x & 3;
    if (node >= N_NODES) return;
    int start = off4[(size_t)node * 4 + Q], end = off4[(size_t)node * 4 + Q + 1];

    float a0x=0,a0y=0,a1x=0,a1y=0,a2x=0,a2y=0,a3x=0,a3y=0;
    float b0x=0,b0y=0,b1x=0,b1y=0,b2x=0,b2y=0,b3x=0,b3y=0;
    int e = start;
    for (; e + 16 <= end; e += 16) {
        int s0=ss[e+0], s1=ss[e+1], s2=ss[e+2],  s3=ss[e+3];
        int s4=ss[e+4], s5=ss[e+5], s6=ss[e+6],  s7=ss[e+7];
        int s8=ss[e+8], s9=ss[e+9], sa=ss[e+10], sb=ss[e+11];
        int sc=ss[e+12],sd=ss[e+13],se=ss[e+14], sf=ss[e+15];
        float2 f0=__half22float2(h2[(size_t)s0*4+j]);
        float2 f1=__half22float2(h2[(size_t)s1*4+j]);
        float2 f2=__half22float2(h2[(size_t)s2*4+j]);
        float2 f3=__half22float2(h2[(size_t)s3*4+j]);
        float2 f4=__half22float2(h2[(size_t)s4*4+j]);
        float2 f5=__half22float2(h2[(size_t)s5*4+j]);
        float2 f6=__half22float2(h2[(size_t)s6*4+j]);
        float2 f7=__half22float2(h2[(size_t)s7*4+j]);
        float2 f8=__half22float2(h2[(size_t)s8*4+j]);
        float2 f9=__half22float2(h2[(size_t)s9*4+j]);
        float2 fa=__half22float2(h2[(size_t)sa*4+j]);
        float2 fb=__half22float2(h2[(size_t)sb*4+j]);
        float2 fc=__half22float2(h2[(size_t)sc*4+j]);
        float2 fd=__half22float2(h2[(size_t)sd*4+j]);
        float2 fe=__half22float2(h2[(size_t)se*4+j]);
        float2 ff=__half22float2(h2[(size_t)sf*4+j]);
        a0x+=f0.x;a0y+=f0.y; a1x+=f1.x;a1y+=f1.y;
        a2x+=f2.x;a2y+=f2.y; a3x+=f3.x;a3y+=f3.y;
        b0x+=f4.x;b0y+=f4.y; b1x+=f5.x;b1y+=f5.y;
        b2x+=f6.x;b2y+=f6.y; b3x+=f7.x;b3y+=f7.y;
        a0x+=f8.x;a0y+=f8.y; a1x+=f9.x;a1y+=f9.y;
        a2x+=fa.x;a2y+=fa.y; a3x+=fb.x;a3y+=fb.y;
        b0x+=fc.x;b0y+=fc.y; b1x+=fd.x;b1y+=fd.y;
        b2x+=fe.x;b2y+=fe.y; b3x+=ff.x;b3y+=ff.y;
    }
    for (; e + 4 <= end; e += 4) {
        int s0=ss[e+0], s1=ss[e+1], s2=ss[e+2], s3=ss[e+3];
        float2 f0=__half22float2(h2[(size_t)s0*4+j]);
        float2 f1=__half22float2(h2[(size_t)s1*4+j]);
        float2 f2=__half22float2(h2[(size_t)s2*4+j]);
        float2 f3=__half22float2(h2[(size_t)s3*4+j]);
        a0x+=f0.x;a0y+=f0.y; a1x+=f1.x;a1y+=f1.y;
        a2x+=f2.x;a2y+=f2.y; a3x+=f3.x;a3y+=f3.y;
    }
    for (; e < end; ++e) {
        float2 f = __half22float2(h2[(size_t)ss[e]*4+j]);
        a0x += f.x; a0y += f.y;
    }
    float rx = ((a0x+a1x)+(a2x+a3x)) + ((b0x+b1x)+(b2x+b3x));
    float ry = ((a0y+a1y)+(a2y+a3y)) + ((b0y+b1y)+(b2y+b3y));
    float* dst = agg + (size_t)node * 8 + j * 2;
    if (Q == 0) {
        f32x2 v = { rx, ry };
        __builtin_nontemporal_store(v, (f32x2*)dst);
    } else {
        f32x2 v = *(const f32x2*)dst;
        v[0] += rx; v[1] += ry;
        __builtin_nontemporal_store(v, (f32x2*)dst);
    }
}

// ---------------------------------------------------------------------------
// transform3: h3 = relu(agg@Wrel + brel + h2@Wroot)  [7 -> 10], streams
// agg (stride 8) + h2; writes h3 (32B rows, pads 0).
// ---------------------------------------------------------------------------
__global__ __launch_bounds__(256) void transform3_kernel(
    const float* __restrict__ agg, const __half2* __restrict__ h2,
    const float* __restrict__ Wrel, const float* __restrict__ brel,
    const float* __restrict__ Wroot,
    __half2* __restrict__ h3)
{
    __shared__ float sWr[70], sWo[70], sb[10];
    int t = threadIdx.x;
    if (t < 70) { sWr[t] = Wrel[t]; sWo[t] = Wroot[t]; }
    if (t < 10) sb[t] = brel[t];
    __syncthreads();
    int i = blockIdx.x * blockDim.x + threadIdx.x;
    if (i >= N_NODES) return;
    const float4* ap = (const float4*)(agg + (size_t)i * 8);
    float4 a0 = ap[0], a1 = ap[1];
    float av[7] = {a0.x, a0.y, a0.z, a0.w, a1.x, a1.y, a1.z};
    float xv[8];
#pragma unroll
    for (int q = 0; q < 4; ++q) {
        float2 f = __half22float2(h2[(size_t)i * 4 + q]);
        xv[2 * q] = f.x; xv[2 * q + 1] = f.y;
    }
    float o_[16];
#pragma unroll
    for (int o = 0; o < 10; ++o) {
        float v = sb[o];
#pragma unroll
        for (int k = 0; k < 7; ++k)
            v += av[k] * sWr[k * 10 + o] + xv[k] * sWo[k * 10 + o];
        o_[o] = fmaxf(v, 0.0f);
    }
#pragma unroll
    for (int o = 10; o < 16; ++o) o_[o] = 0.0f;
    u32x4 v0 = { h2u(__floats2half2_rn(o_[0], o_[1])),
                 h2u(__floats2half2_rn(o_[2], o_[3])),
                 h2u(__floats2half2_rn(o_[4], o_[5])),
                 h2u(__floats2half2_rn(o_[6], o_[7])) };
    u32x4 v1 = { h2u(__floats2half2_rn(o_[8], o_[9])),
                 h2u(__floats2half2_rn(o_[10], o_[11])),
                 h2u(__floats2half2_rn(o_[12], o_[13])),
                 h2u(__floats2half2_rn(o_[14], o_[15])) };
    __builtin_nontemporal_store(v0, (u32x4*)(h3 + (size_t)i * 8));
    __builtin_nontemporal_store(v1, (u32x4*)(h3 + (size_t)i * 8 + 4));
}

// ---------------------------------------------------------------------------
// Layer-4 gather, cache-blocked: pass Q touches only h3 quartile (4MB slice).
// 8 lanes/node, 16-deep unroll. Pass 0 nt-stores agg (stride 16); 1-3 RMW.
// ---------------------------------------------------------------------------
template<int Q>
__global__ __launch_bounds__(256) void gather4_kernel(
    const int* __restrict__ off4, const int* __restrict__ ss,
    const __half2* __restrict__ h3, float* __restrict__ agg)
{
    int node = blockIdx.x * 32 + (threadIdx.x >> 3);
    int j = threadIdx.x & 7;
    if (node >= N_NODES) return;
    int start = off4[(size_t)node * 4 + Q], end = off4[(size_t)node * 4 + Q + 1];

    float a0x=0,a0y=0,a1x=0,a1y=0,a2x=0,a2y=0,a3x=0,a3y=0;
    float b0x=0,b0y=0,b1x=0,b1y=0,b2x=0,b2y=0,b3x=0,b3y=0;
    int e = start;
    for (; e + 16 <= end; e += 16) {
        int s0=ss[e+0], s1=ss[e+1], s2=ss[e+2],  s3=ss[e+3];
        int s4=ss[e+4], s5=ss[e+5], s6=ss[e+6],  s7=ss[e+7];
        int s8=ss[e+8], s9=ss[e+9], sa=ss[e+10], sb=ss[e+11];
        int sc=ss[e+12],sd=ss[e+13],se=ss[e+14], sf=ss[e+15];
        float2 f0=__half22float2(h3[(size_t)s0*8+j]);
        float2 f1=__half22float2(h3[(size_t)s1*8+j]);
        float2 f2=__half22float2(h3[(size_t)s2*8+j]);
        float2 f3=__half22float2(h3[(size_t)s3*8+j]);
        float2 f4=__half22float2(h3[(size_t)s4*8+j]);
        float2 f5=__half22float2(h3[(size_t)s5*8+j]);
        float2 f6=__half22float2(h3[(size_t)s6*8+j]);
        float2 f7=__half22float2(h3[(size_t)s7*8+j]);
        float2 f8=__half22float2(h3[(size_t)s8*8+j]);
        float2 f9=__half22float2(h3[(size_t)s9*8+j]);
        float2 fa=__half22float2(h3[(size_t)sa*8+j]);
        float2 fb=__half22float2(h3[(size_t)sb*8+j]);
        float2 fc=__half22float2(h3[(size_t)sc*8+j]);
        float2 fd=__half22float2(h3[(size_t)sd*8+j]);
        float2 fe=__half22float2(h3[(size_t)se*8+j]);
        float2 ff=__half22float2(h3[(size_t)sf*8+j]);
        a0x+=f0.x;a0y+=f0.y; a1x+=f1.x;a1y+=f1.y;
        a2x+=f2.x;a2y+=f2.y; a3x+=f3.x;a3y+=f3.y;
        b0x+=f4.x;b0y+=f4.y; b1x+=f5.x;b1y+=f5.y;
        b2x+=f6.x;b2y+=f6.y; b3x+=f7.x;b3y+=f7.y;
        a0x+=f8.x;a0y+=f8.y; a1x+=f9.x;a1y+=f9.y;
        a2x+=fa.x;a2y+=fa.y; a3x+=fb.x;a3y+=fb.y;
        b0x+=fc.x;b0y+=fc.y; b1x+=fd.x;b1y+=fd.y;
        b2x+=fe.x;b2y+=fe.y; b3x+=ff.x;b3y+=ff.y;
    }
    for (; e + 4 <= end; e += 4) {
        int s0=ss[e+0], s1=ss[e+1], s2=ss[e+2], s3=ss[e+3];
        float2 f0=__half22float2(h3[(size_t)s0*8+j]);
        float2 f1=__half22float2(h3[(size_t)s1*8+j]);
        float2 f2=__half22float2(h3[(size_t)s2*8+j]);
        float2 f3=__half22float2(h3[(size_t)s3*8+j]);
        a0x+=f0.x;a0y+=f0.y; a1x+=f1.x;a1y+=f1.y;
        a2x+=f2.x;a2y+=f2.y; a3x+=f3.x;a3y+=f3.y;
    }
    for (; e < end; ++e) {
        float2 f = __half22float2(h3[(size_t)ss[e]*8+j]);
        a0x += f.x; a0y += f.y;
    }
    float rx = ((a0x+a1x)+(a2x+a3x)) + ((b0x+b1x)+(b2x+b3x));
    float ry = ((a0y+a1y)+(a2y+a3y)) + ((b0y+b1y)+(b2y+b3y));
    float* dst = agg + (size_t)node * 16 + j * 2;
    if (Q == 0) {
        f32x2 v = { rx, ry };
        __builtin_nontemporal_store(v, (f32x2*)dst);
    } else {
        f32x2 v = *(const f32x2*)dst;
        v[0] += rx; v[1] += ry;
        __builtin_nontemporal_store(v, (f32x2*)dst);
    }
}

// ---------------------------------------------------------------------------
// layer4 transform + 3-layer MLP (separate kernel; streams agg + h3).
// ---------------------------------------------------------------------------
__global__ __launch_bounds__(256) void layer4_mlp_kernel(
    const float* __restrict__ agg, const __half2* __restrict__ h3,
    const float* __restrict__ g4Wrel, const float* __restrict__ g4brel,
    const float* __restrict__ g4Wroot,
    const float* __restrict__ fc1W, const float* __restrict__ fc1b,
    const float* __restrict__ fc2W, const float* __restrict__ fc2b,
    const float* __restrict__ fc3W, const float* __restrict__ fc3b,
    float* __restrict__ out)
{
    __shared__ float s[1680];
    float* sWrel  = s;            // 160
    float* sbrel  = s + 160;      // 16
    float* sWroot = s + 176;      // 160
    float* sfc1W  = s + 336;      // 512
    float* sfc1b  = s + 848;      // 32
    float* sfc2W  = s + 880;      // 512
    float* sfc2b  = s + 1392;     // 16
    float* sfc3W  = s + 1408;     // 256
    float* sfc3b  = s + 1664;     // 16
    int t = threadIdx.x;
    for (int i = t; i < 160; i += 256) { sWrel[i] = g4Wrel[i]; sWroot[i] = g4Wroot[i]; }
    for (int i = t; i < 512; i += 256) { sfc1W[i] = fc1W[i]; sfc2W[i] = fc2W[i]; }
    if (t < 256) sfc3W[t] = fc3W[t];
    if (t < 32)  sfc1b[t] = fc1b[t];
    if (t < 16)  { sbrel[t] = g4brel[t]; sfc2b[t] = fc2b[t]; sfc3b[t] = fc3b[t]; }
    __syncthreads();

    int i = blockIdx.x * blockDim.x + threadIdx.x;
    if (i >= N_NODES) return;

    const float4* ap = (const float4*)(agg + (size_t)i * 16);
    float4 a0 = ap[0], a1 = ap[1], a2 = ap[2];
    float a[10] = {a0.x, a0.y, a0.z, a0.w, a1.x, a1.y, a1.z, a1.w, a2.x, a2.y};
    float xin[10];
#pragma unroll
    for (int q = 0; q < 5; ++q) {
        float2 f = __half22float2(h3[(size_t)i * 8 + q]);
        xin[2 * q] = f.x; xin[2 * q + 1] = f.y;
    }

    float h4[16];
#pragma unroll
    for (int o = 0; o < 16; ++o) {
        float v = sbrel[o];
#pragma unroll
        for (int k = 0; k < 10; ++k)
            v += a[k] * sWrel[k * 16 + o] + xin[k] * sWroot[k * 16 + o];
        h4[o] = fmaxf(v, 0.0f);
    }
    float m1[32];
#pragma unroll
    for (int o = 0; o < 32; ++o) {
        float v = sfc1b[o];
#pragma unroll
        for (int k = 0; k < 16; ++k) v += h4[k] * sfc1W[k * 32 + o];
        m1[o] = fmaxf(v, 0.0f);
    }
    float m2[16];
#pragma unroll
    for (int o = 0; o < 16; ++o) {
        float v = sfc2b[o];
#pragma unroll
        for (int k = 0; k < 32; ++k) v += m1[k] * sfc2W[k * 16 + o];
        m2[o] = fmaxf(v, 0.0f);
    }
    float r[16];
#pragma unroll
    for (int o = 0; o < 16; ++o) {
        float v = sfc3b[o];
#pragma unroll
        for (int k = 0; k < 16; ++k) v += m2[k] * sfc3W[k * 16 + o];
        r[o] = v;
    }
#pragma unroll
    for (int q = 0; q < 4; ++q) {
        f32x4 v = { r[q*4+0], r[q*4+1], r[q*4+2], r[q*4+3] };
        __builtin_nontemporal_store(v, (f32x4*)(out + (size_t)i * 16 + q * 4));
    }
}

// ---------------------------------------------------------------------------
extern "C" void kernel_launch(void* const* d_in, const int* in_sizes, int n_in,
                              void* d_out, int out_size, void* d_ws, size_t ws_size,
                              hipStream_t stream) {
    const float* x        = (const float*)d_in[0];
    const int*   ei       = (const int*)d_in[1];
    const float* g1_Wrel  = (const float*)d_in[2];
    const float* g1_brel  = (const float*)d_in[3];
    const float* g1_Wroot = (const float*)d_in[4];
    const float* g2_Wrel  = (const float*)d_in[5];
    const float* g2_brel  = (const float*)d_in[6];
    const float* g2_Wroot = (const float*)d_in[7];
    const float* g3_Wrel  = (const float*)d_in[8];
    const float* g3_brel  = (const float*)d_in[9];
    const float* g3_Wroot = (const float*)d_in[10];
    const float* g4_Wrel  = (const float*)d_in[11];
    const float* g4_brel  = (const float*)d_in[12];
    const float* g4_Wroot = (const float*)d_in[13];
    const float* fc1_W    = (const float*)d_in[14];
    const float* fc1_b    = (const float*)d_in[15];
    const float* fc2_W    = (const float*)d_in[16];
    const float* fc2_b    = (const float*)d_in[17];
    const float* fc3_W    = (const float*)d_in[18];
    const float* fc3_b    = (const float*)d_in[19];
    float* out = (float*)d_out;

    const int* srcp = ei;
    const int* dstp = ei + N_EDGES;

    // ---- workspace layout (256B aligned), ~148 MiB ----
    char* p = (char*)d_ws;
    auto alloc = [&](size_t bytes) {
        char* r = p;
        p += (bytes + 255) & ~(size_t)255;
        return r;
    };
    // region A: h1+h2+h3+agg+pad (74 MiB), aliased by pairs2 (64.9 MiB).
    __half2* h1  = (__half2*)alloc((size_t)N_NODES * 2 * sizeof(__half2));  //  4 MB
    __half2* h2  = (__half2*)alloc((size_t)N_NODES * 4 * sizeof(__half2));  //  8 MB
    __half2* h3  = (__half2*)alloc((size_t)N_NODES * 8 * sizeof(__half2));  // 16 MB
    float*   agg = (float*)  alloc((size_t)N_NODES * 16 * 4);               // 32 MB
    alloc((size_t)14 * 1024 * 1024);                                        // pad
    unsigned int* pairs2 = (unsigned int*)h1;          // 977*17408*4 = 64.9 MiB
    // region B: pairs1 (bin1 out / bin2 in), reused as sorted_src after bin2.
    int* sorted_src = (int*)alloc((size_t)NSUPER * CAP1 * 4);  // 63.9 MiB
    unsigned int* pairs1 = (unsigned int*)sorted_src;
    int*   off4  = (int*)alloc(((size_t)N_NODES * 4 + 1) * 4); //  8 MB
    float* agg1  = (float*)alloc((size_t)N_NODES * 4);         //  2 MB
    int*   bcur1 = (int*)alloc((size_t)NSUPER * 4);
    int*   bcur2 = (int*)alloc((size_t)NBUCKET * 4);
    int*   bbase = (int*)alloc((size_t)(NBUCKET + 1) * 4);

    const int TB = 256;
    const int node_blocks = (N_NODES + TB - 1) / TB;

    // ---- CSR build: bin1 -> bin2 -> scan -> staged single-pass sort ----
    init_bcur_kernel<<<2, 512, 0, stream>>>(bcur1, bcur2);
    bin1_kernel<<<B1_NBLK, 256, 0, stream>>>(srcp, dstp, bcur1, pairs1);
    bin2_kernel<<<NSUPER * B2_PER_SUPER, 256, 0, stream>>>(bcur1, bcur2, pairs1, pairs2);
    bucket_scan_kernel<<<1, 512, 0, stream>>>(bcur2, bbase);
    bucket_sort512_kernel<<<NBUCKET, 512, 0, stream>>>(
        bcur2, bbase, pairs2, x, off4, sorted_src, agg1);

    // ---- layer 1: transform only (agg fused in sort); h1 fp16 ----
    transform1_kernel<<<node_blocks, TB, 0, stream>>>(
        agg1, x, g1_Wrel, g1_brel, g1_Wroot, h1);

    // ---- layer 2: fused gather+transform ----
    gather2t_kernel<<<(N_NODES + 127) / 128, TB, 0, stream>>>(
        off4, sorted_src, h1, g2_Wrel, g2_brel, g2_Wroot, h2);

    // ---- layer 3: 4 cache-blocked gather passes (2MB h2 slices) + transform ----
    const int g3_blocks = (N_NODES + 63) / 64;
    gather3_kernel<0><<<g3_blocks, TB, 0, stream>>>(off4, sorted_src, h2, agg);
    gather3_kernel<1><<<g3_blocks, TB, 0, stream>>>(off4, sorted_src, h2, agg);
    gather3_kernel<2><<<g3_blocks, TB, 0, stream>>>(off4, sorted_src, h2, agg);
    gather3_kernel<3><<<g3_blocks, TB, 0, stream>>>(off4, sorted_src, h2, agg);
    transform3_kernel<<<node_blocks, TB, 0, stream>>>(
        agg, h2, g3_Wrel, g3_brel, g3_Wroot, h3);

    // ---- layer 4: 4 cache-blocked gather passes, then transform+MLP ----
    const int g4_blocks = (N_NODES + 31) / 32;
    gather4_kernel<0><<<g4_blocks, TB, 0, stream>>>(off4, sorted_src, h3, agg);
    gather4_kernel<1><<<g4_blocks, TB, 0, stream>>>(off4, sorted_src, h3, agg);
    gather4_kernel<2><<<g4_blocks, TB, 0, stream>>>(off4, sorted_src, h3, agg);
    gather4_kernel<3><<<g4_blocks, TB, 0, stream>>>(off4, sorted_src, h3, agg);
    layer4_mlp_kernel<<<node_blocks, TB, 0, stream>>>(
        agg, h3, g4_Wrel, g4_brel, g4_Wroot,
        fc1_W, fc1_b, fc2_W, fc2_b, fc3_W, fc3_b, out);
}